// Round 23
// baseline (754.432 us; speedup 1.0000x reference)
//
#include <hip/hip_runtime.h>
#include <cstdint>
#include <cstddef>

typedef __bf16 bf16x8 __attribute__((ext_vector_type(8)));
typedef float f32x4 __attribute__((ext_vector_type(4)));
typedef unsigned short u16x8 __attribute__((ext_vector_type(8)));
typedef unsigned short u16x4 __attribute__((ext_vector_type(4)));

#define DEV __device__ __forceinline__

DEV unsigned short f2b(float f) {
    __bf16 b = (__bf16)f;                      // native RTNE cvt
    return __builtin_bit_cast(unsigned short, b);
}

DEV float fast_rcp(float x) { return __builtin_amdgcn_rcpf(x); }  // v_rcp_f32, ~1ulp

// sigmoid-form GELU with HW reciprocal (~6 VALU ops). Tails saturate correctly.
DEV float gelu_f(float v) {
    float e = __expf(-1.702f * v);
    return v * fast_rcp(1.f + e);
}

// ---------------------------------------------------------------- merged weight converts (one launch)
__global__ __launch_bounds__(256) void cvt_all(const float* __restrict__ s0, const float* __restrict__ s1,
                                               const float* __restrict__ s2, const float* __restrict__ s3,
                                               unsigned short* __restrict__ d0, unsigned short* __restrict__ d1,
                                               unsigned short* __restrict__ d2, unsigned short* __restrict__ d3) {
    int b = blockIdx.x;
    const float* s; unsigned short* d; int lb;
    if (b < 768)       { s = s0; d = d0; lb = b; }
    else if (b < 1024) { s = s1; d = d1; lb = b - 768; }
    else if (b < 2048) { s = s2; d = d2; lb = b - 1024; }
    else               { s = s3; d = d3; lb = b - 2048; }
    int i = lb * 256 + threadIdx.x;
    float4 f = ((const float4*)s)[i];
    u16x4 o;
    o[0] = f2b(f.x); o[1] = f2b(f.y); o[2] = f2b(f.z); o[3] = f2b(f.w);
    ((u16x4*)d)[i] = o;
}

// ---------------------------------------------------------------- rel-pos bias table: bias[h][i][j], fp32
__global__ __launch_bounds__(256) void bias_pre(const float* __restrict__ rpb, float* __restrict__ bias) {
    int idx = blockIdx.x * 256 + threadIdx.x;      // 16*4096 = 65536
    int h = idx >> 12, ij = idx & 4095;
    int i = ij >> 6, j = ij & 63;
    int r = ((i >> 3) - (j >> 3) + 7) * 15 + ((i & 7) - (j & 7) + 7);
    bias[idx] = rpb[r * 16 + h];
}

// ---------------------------------------------------------------- ada = silu(t)@W^T + b
__global__ __launch_bounds__(256) void ada_kernel(const float* __restrict__ t_emb,
                                                  const float* __restrict__ aw,
                                                  const float* __restrict__ ab,
                                                  float* __restrict__ ada) {
    __shared__ float st[512];
    int b = blockIdx.x, jc = blockIdx.y;
    for (int k = threadIdx.x; k < 512; k += 256) {
        float t = t_emb[b * 512 + k];
        st[k] = t * fast_rcp(1.f + __expf(-t));
    }
    __syncthreads();
    int j = jc * 256 + threadIdx.x;
    const float* wr = aw + (size_t)j * 512;
    float acc = ab[j];
    for (int k = 0; k < 512; ++k) acc += st[k] * wr[k];
    ada[b * 2048 + j] = acc;
}

// ---------------------------------------------------------------- LN + modulate (+roll/window for WIN=1)
template <int WIN>
__global__ __launch_bounds__(256, 4) void ln_mod(const float* __restrict__ xin,
                                                 const float* __restrict__ g,
                                                 const float* __restrict__ beta,
                                                 const float* __restrict__ ada,
                                                 unsigned short* __restrict__ out) {
    int wv = threadIdx.x >> 6, l = threadIdx.x & 63;
    int tok = blockIdx.x * 4 + wv;
    int bb;
    const float* src;
    if (WIN) {
        int w = tok >> 6, t = tok & 63;
        bb = w >> 6;
        int nw = w & 63;
        int y = (((nw >> 3) << 3) + (t >> 3) + 4) & 63;
        int x = (((nw & 7) << 3) + (t & 7) + 4) & 63;
        src = xin + ((size_t)(bb * 64 + y) * 64 + x) * 512;
    } else {
        bb = tok >> 12;
        src = xin + (size_t)tok * 512;
    }
    const float4* f4 = (const float4*)src;
    float4 v0 = f4[l * 2];
    float4 v1 = f4[l * 2 + 1];
    float s = v0.x + v0.y + v0.z + v0.w + v1.x + v1.y + v1.z + v1.w;
    float ss = v0.x * v0.x + v0.y * v0.y + v0.z * v0.z + v0.w * v0.w +
               v1.x * v1.x + v1.y * v1.y + v1.z * v1.z + v1.w * v1.w;
#pragma unroll
    for (int d = 1; d < 64; d <<= 1) {
        s += __shfl_xor(s, d, 64);
        ss += __shfl_xor(ss, d, 64);
    }
    float mean = s * (1.f / 512.f);
    float var = ss * (1.f / 512.f) - mean * mean;
    float rstd = rsqrtf(var + 1e-5f);
    const float* sh = ada + bb * 2048 + (WIN ? 0 : 1024);
    const float* sc = ada + bb * 2048 + (WIN ? 512 : 1536);
    int c = l * 8;
    u16x8 o;
#pragma unroll
    for (int q = 0; q < 8; ++q) {
        float xv = (q < 4) ? (&v0.x)[q] : (&v1.x)[q - 4];
        float nv = (xv - mean) * rstd * g[c + q] + beta[c + q];
        nv = nv * (1.f + sc[c + q]) + sh[c + q];
        o[q] = f2b(nv);
    }
    *(u16x8*)(out + (size_t)tok * 512 + c) = o;
}

// ---------------------------------------------------------------- 128x128 GEMM, BK=64, single buffer, SPLIT-KK (r14 best)
// barrier -> read kk0(8) -> 16 MFMA -> read kk1(8) -> barrier -> stage(kt+1) -> 16 MFMA.
// XOR(r&7) involution swizzle; 32KB LDS. Coalesced bf16 epilogue via LDS.
// EPI 0: +bias -> bf16                EPI 1: gelu(+bias) -> bf16
// EPI 2: +bias +window-reverse/roll +resid -> fp32   EPI 3: +bias, out += (fp32)
// EPI 4: +bias -> bf16 in head-blocked layout [w][p][h][64][32] (qkv for attn)
template <int EPI>
__global__ __launch_bounds__(256, 4) void gemm_bt(const unsigned short* __restrict__ A,
                                                  const unsigned short* __restrict__ B,
                                                  const float* __restrict__ bias,
                                                  void* __restrict__ outv,
                                                  const float* __restrict__ resid,
                                                  int N, int K, int m0g, int nbx) {
    __shared__ __align__(16) unsigned short sA[128 * 64];
    __shared__ __align__(16) unsigned short sB[128 * 64];
    const int tid = threadIdx.x;
    // T1: XCD-aware swizzle (grid always a multiple of 8)
    const int cpx = gridDim.x >> 3;
    const int wg = (blockIdx.x & 7) * cpx + (blockIdx.x >> 3);
    const int by = wg / nbx, bx = wg - by * nbx;
    const int bm = by * 128, bn = bx * 128;
    const int l = tid & 63, wv = tid >> 6;
    const int wm = (wv >> 1) * 64, wn = (wv & 1) * 64;
    const int lrow = l & 15, lg = l >> 4;

    auto stage = [&](int k0) {
#pragma unroll
        for (int inst = 0; inst < 4; ++inst) {
            int S = inst * 256 + tid;          // 16B slot in [0,1024): row r, slot j of 8
            int r = S >> 3, j = S & 7;
            int c0 = j ^ (r & 7);              // involutive swizzle on global source
            const unsigned short* gA = A + (size_t)(bm + r) * K + k0 + c0 * 8;
            __builtin_amdgcn_global_load_lds((const __attribute__((address_space(1))) void*)gA,
                                             (__attribute__((address_space(3))) void*)&sA[S * 8], 16, 0, 0);
        }
#pragma unroll
        for (int inst = 0; inst < 4; ++inst) {
            int S = inst * 256 + tid;
            int r = S >> 3, j = S & 7;
            int c0 = j ^ (r & 7);
            const unsigned short* gB = B + (size_t)(bn + r) * K + k0 + c0 * 8;
            __builtin_amdgcn_global_load_lds((const __attribute__((address_space(1))) void*)gB,
                                             (__attribute__((address_space(3))) void*)&sB[S * 8], 16, 0, 0);
        }
    };

    f32x4 acc[4][4] = {};
    const int nk = K >> 6;                     // 8 (K=512) or 32 (K=2048)
    stage(0);
    for (int kt = 0; kt < nk; ++kt) {
        __syncthreads();                       // staging of kt landed
        {
            bf16x8 a0[4], b0[4];               // kk = 0 fragments only (32 VGPR)
#pragma unroll
            for (int m = 0; m < 4; ++m) {
                int R = wm + m * 16 + lrow;
                a0[m] = *(const bf16x8*)(sA + R * 64 + ((lg ^ (R & 7)) * 8));
            }
#pragma unroll
            for (int n = 0; n < 4; ++n) {
                int C = wn + n * 16 + lrow;
                b0[n] = *(const bf16x8*)(sB + C * 64 + ((lg ^ (C & 7)) * 8));
            }
#pragma unroll
            for (int m = 0; m < 4; ++m)
#pragma unroll
                for (int n = 0; n < 4; ++n)
                    acc[m][n] = __builtin_amdgcn_mfma_f32_16x16x32_bf16(a0[m], b0[n], acc[m][n], 0, 0, 0);
        }
        bf16x8 a1[4], b1[4];                   // kk = 1 fragments
#pragma unroll
        for (int m = 0; m < 4; ++m) {
            int R = wm + m * 16 + lrow;
            a1[m] = *(const bf16x8*)(sA + R * 64 + (((4 | lg) ^ (R & 7)) * 8));
        }
#pragma unroll
        for (int n = 0; n < 4; ++n) {
            int C = wn + n * 16 + lrow;
            b1[n] = *(const bf16x8*)(sB + C * 64 + (((4 | lg) ^ (C & 7)) * 8));
        }
        __syncthreads();                       // all reads done -> buffer overwritable
        if (kt + 1 < nk) stage((kt + 1) * 64); // DMA fills while MFMA(kk1) runs
#pragma unroll
        for (int m = 0; m < 4; ++m)
#pragma unroll
            for (int n = 0; n < 4; ++n)
                acc[m][n] = __builtin_amdgcn_mfma_f32_16x16x32_bf16(a1[m], b1[n], acc[m][n], 0, 0, 0);
    }

    if constexpr (EPI == 0 || EPI == 1 || EPI == 4) {
        unsigned short* o = (unsigned short*)outv;
        unsigned short* tb = &sA[0] + wv * 1152;   // per-wave 16x72 u16
        float bv[4];
#pragma unroll
        for (int n = 0; n < 4; ++n) bv[n] = bias[bn + wn + n * 16 + lrow];
#pragma unroll
        for (int m = 0; m < 4; ++m) {
#pragma unroll
            for (int n = 0; n < 4; ++n)
#pragma unroll
                for (int r = 0; r < 4; ++r) {
                    float v = acc[m][n][r] + bv[n];
                    if constexpr (EPI == 1) v = gelu_f(v);
                    tb[(lg * 4 + r) * 72 + n * 16 + lrow] = f2b(v);
                }
#pragma unroll
            for (int it = 0; it < 2; ++it) {
                int rr = it * 8 + (l >> 3);
                int cc = (l & 7) * 8;
                u16x8 vv = *(const u16x8*)(tb + rr * 72 + cc);
                if constexpr (EPI == 4) {
                    int row = bm + wm + m * 16 + rr;
                    int col = bn + wn + cc;
                    int w_ = row >> 6, t_ = row & 63;
                    size_t dst = (size_t)w_ * 98304 + (size_t)(col >> 9) * 32768 +
                                 (size_t)((col >> 5) & 15) * 2048 + t_ * 32 + (col & 31);
                    *(u16x8*)(o + dst) = vv;
                } else {
                    *(u16x8*)(o + (size_t)(bm + wm + m * 16 + rr) * N + bn + wn + cc) = vv;
                }
            }
        }
    } else if constexpr (EPI == 2) {
        float* o = (float*)outv;
#pragma unroll
        for (int m = 0; m < 4; ++m)
#pragma unroll
            for (int r = 0; r < 4; ++r) {
                int row = bm + wm + m * 16 + lg * 4 + r;
                int wdx = row >> 6, t = row & 63;
                int bb = wdx >> 6, nw = wdx & 63;
                int Y = (((nw >> 3) << 3) + (t >> 3) + 4) & 63;
                int X = (((nw & 7) << 3) + (t & 7) + 4) & 63;
                size_t base = ((size_t)(bb * 64 + Y) * 64 + X) * 512;
#pragma unroll
                for (int n = 0; n < 4; ++n) {
                    int col = bn + wn + n * 16 + lrow;
                    o[base + col] = resid[base + col] + acc[m][n][r] + bias[col];
                }
            }
    } else {  // EPI == 3
        float* o = (float*)outv;
#pragma unroll
        for (int m = 0; m < 4; ++m)
#pragma unroll
            for (int r = 0; r < 4; ++r) {
                size_t rg = (size_t)(m0g + bm + wm + m * 16 + lg * 4 + r) * 512;
#pragma unroll
                for (int n = 0; n < 4; ++n) {
                    int col = bn + wn + n * 16 + lrow;
                    o[rg + col] += acc[m][n][r] + bias[col];
                }
            }
    }
}

// ---------------------------------------------------------------- attention: 1 wave per (window, head)
// qkv in head-blocked layout [w][p][h][64][32] -> all q/k/v reads fully coalesced.
// Output staged per-wave in LDS (stride-40 rows) -> 64B-contiguous row writes.
__global__ __launch_bounds__(256, 2) void attn_kernel(const unsigned short* __restrict__ qkv,
                                                      const float* __restrict__ bias_t,
                                                      unsigned short* __restrict__ out) {
    __shared__ __align__(16) unsigned short P_lds[4][64 * 72];
    __shared__ __align__(16) unsigned short Vt[4][32 * 72];
    const int wv = threadIdx.x >> 6, l = threadIdx.x & 63;
    const int u = blockIdx.x * 4 + wv;
    const int w = u >> 4, h = u & 15;
    const int lrow = l & 15, lg = l >> 4;
    const float SCALE = 0.17677669529663687f;  // 32^-0.5

    const unsigned short* qb = qkv + (size_t)w * 98304 + (size_t)h * 2048;

    bf16x8 qf[4], kf[4];
#pragma unroll
    for (int i = 0; i < 4; ++i) {
        qf[i] = *(const bf16x8*)(qb + (16 * i + lrow) * 32 + lg * 8);
        kf[i] = *(const bf16x8*)(qb + 32768 + (16 * i + lrow) * 32 + lg * 8);
    }
    f32x4 S[4][4] = {};
#pragma unroll
    for (int mi = 0; mi < 4; ++mi)
#pragma unroll
        for (int ni = 0; ni < 4; ++ni)
            S[mi][ni] = __builtin_amdgcn_mfma_f32_16x16x32_bf16(qf[mi], kf[ni], S[mi][ni], 0, 0, 0);

    u16x8 vreg[4];
    const unsigned short* vp = qb + 65536 + (size_t)l * 32;
#pragma unroll
    for (int d0 = 0; d0 < 4; ++d0) vreg[d0] = *(const u16x8*)(vp + d0 * 8);

    const int nw = w & 63;
    const int wh0 = (nw >> 3) << 3, ww0 = (nw & 7) << 3;
    auto region = [&](int t) -> int {
        int yy = wh0 + (t >> 3), xx = ww0 + (t & 7);
        int rh = (yy < 56) ? 0 : ((yy < 60) ? 1 : 2);
        int rw = (xx < 56) ? 0 : ((xx < 60) ? 1 : 2);
        return rh * 3 + rw;
    };
    int jreg[4], jcol[4];
#pragma unroll
    for (int ni = 0; ni < 4; ++ni) {
        jcol[ni] = 16 * ni + lrow;
        jreg[ni] = region(jcol[ni]);
    }
    const float* bh = bias_t + h * 4096;
    unsigned short* pl = &P_lds[wv][0];
#pragma unroll
    for (int mi = 0; mi < 4; ++mi)
#pragma unroll
        for (int r = 0; r < 4; ++r) {
            int i = 16 * mi + 4 * lg + r;
            int ireg = region(i);
            const float* bi = bh + i * 64;
            float pv[4];
            float mx = -1e30f;
#pragma unroll
            for (int ni = 0; ni < 4; ++ni) {
                float val = S[mi][ni][r] * SCALE + bi[jcol[ni]];
                if (ireg != jreg[ni]) val -= 100.f;
                pv[ni] = val;
                mx = fmaxf(mx, val);
            }
#pragma unroll
            for (int d = 1; d < 16; d <<= 1) mx = fmaxf(mx, __shfl_xor(mx, d, 64));
            float sum = 0.f;
#pragma unroll
            for (int ni = 0; ni < 4; ++ni) {
                pv[ni] = __expf(pv[ni] - mx);
                sum += pv[ni];
            }
#pragma unroll
            for (int d = 1; d < 16; d <<= 1) sum += __shfl_xor(sum, d, 64);
            float inv = fast_rcp(sum);         // sum >= 1, well-conditioned
#pragma unroll
            for (int ni = 0; ni < 4; ++ni) pl[i * 72 + jcol[ni]] = f2b(pv[ni] * inv);
        }

    unsigned short* vt = &Vt[wv][0];
#pragma unroll
    for (int d0 = 0; d0 < 4; ++d0)
#pragma unroll
        for (int q = 0; q < 8; ++q) vt[(d0 * 8 + q) * 72 + l] = vreg[d0][q];

    __syncthreads();

    f32x4 O[4][2] = {};
#pragma unroll
    for (int ks = 0; ks < 2; ++ks) {
        bf16x8 pa[4], vb[2];
#pragma unroll
        for (int mi = 0; mi < 4; ++mi)
            pa[mi] = *(const bf16x8*)(pl + (16 * mi + lrow) * 72 + ks * 32 + lg * 8);
#pragma unroll
        for (int ni = 0; ni < 2; ++ni)
            vb[ni] = *(const bf16x8*)(vt + (16 * ni + lrow) * 72 + ks * 32 + lg * 8);
#pragma unroll
        for (int mi = 0; mi < 4; ++mi)
#pragma unroll
            for (int ni = 0; ni < 2; ++ni)
                O[mi][ni] = __builtin_amdgcn_mfma_f32_16x16x32_bf16(pa[mi], vb[ni], O[mi][ni], 0, 0, 0);
    }

    // ---- stage O in per-wave LDS (stride 40 u16, 16B-aligned rows), then
    //      one 64B-contiguous row write per lane (replaces 32 scalar 2B stores).
    unsigned short* ostg = pl;                 // P_lds[wv] is dead now (same-wave reuse)
#pragma unroll
    for (int mi = 0; mi < 4; ++mi)
#pragma unroll
        for (int ni = 0; ni < 2; ++ni)
#pragma unroll
            for (int r = 0; r < 4; ++r)
                ostg[(16 * mi + 4 * lg + r) * 40 + 16 * ni + lrow] = f2b(O[mi][ni][r]);
    unsigned short* op = out + (size_t)(w * 64 + l) * 512 + h * 32;
#pragma unroll
    for (int q4 = 0; q4 < 4; ++q4)
        *(u16x8*)(op + q4 * 8) = *(const u16x8*)(ostg + l * 40 + q4 * 8);
}

// ---------------------------------------------------------------- launch
extern "C" void kernel_launch(void* const* d_in, const int* in_sizes, int n_in,
                              void* d_out, int out_size, void* d_ws, size_t ws_size,
                              hipStream_t stream) {
    const float* x      = (const float*)d_in[0];
    const float* t_emb  = (const float*)d_in[1];
    const float* n1g    = (const float*)d_in[2];
    const float* n1b    = (const float*)d_in[3];
    const float* qkv_w  = (const float*)d_in[4];
    const float* qkv_b  = (const float*)d_in[5];
    const float* proj_w = (const float*)d_in[6];
    const float* proj_b = (const float*)d_in[7];
    const float* rpb    = (const float*)d_in[8];
    const float* n2g    = (const float*)d_in[9];
    const float* n2b    = (const float*)d_in[10];
    const float* fc1_w  = (const float*)d_in[11];
    const float* fc1_b  = (const float*)d_in[12];
    const float* fc2_w  = (const float*)d_in[13];
    const float* fc2_b  = (const float*)d_in[14];
    const float* ada_w  = (const float*)d_in[15];
    const float* ada_b  = (const float*)d_in[16];
    float* out = (float*)d_out;

    char* p = (char*)d_ws;
    auto alloc = [&](size_t bytes) { void* r = (void*)p; p += (bytes + 255) & ~(size_t)255; return r; };
    unsigned short* Wq  = (unsigned short*)alloc((size_t)1536 * 512 * 2);
    unsigned short* Wp  = (unsigned short*)alloc((size_t)512 * 512 * 2);
    unsigned short* W1  = (unsigned short*)alloc((size_t)2048 * 512 * 2);
    unsigned short* W2  = (unsigned short*)alloc((size_t)512 * 2048 * 2);
    float*          bias_t = (float*)alloc((size_t)16 * 4096 * 4);
    float*          ada = (float*)alloc((size_t)16 * 2048 * 4);
    unsigned short* bufA = (unsigned short*)alloc((size_t)65536 * 512 * 2);   // xw / attn_out / xw2
    unsigned short* bufB = (unsigned short*)alloc((size_t)65536 * 1536 * 2);  // qkv / mlp hidden

    // 1. merged weight converts + bias table + adaLN
    cvt_all<<<3072, 256, 0, stream>>>(qkv_w, proj_w, fc1_w, fc2_w, Wq, Wp, W1, W2);
    bias_pre<<<256, 256, 0, stream>>>(rpb, bias_t);
    ada_kernel<<<dim3(16, 8), 256, 0, stream>>>(t_emb, ada_w, ada_b, ada);
    // 3. LN1 + modulate + roll + window partition
    ln_mod<1><<<16384, 256, 0, stream>>>(x, n1g, n1b, ada, bufA);
    // 4. qkv GEMM -> head-blocked layout (grid 6144, %8==0)
    gemm_bt<4><<<6144, 256, 0, stream>>>(bufA, Wq, qkv_b, bufB, nullptr, 1536, 512, 0, 12);
    // 5. windowed attention
    attn_kernel<<<4096, 256, 0, stream>>>(bufB, bias_t, bufA);
    // 6. proj GEMM + window reverse + roll + residual -> d_out (fp32)  (grid 2048)
    gemm_bt<2><<<2048, 256, 0, stream>>>(bufA, Wp, proj_b, out, x, 512, 512, 0, 4);
    // 7. LN2 + modulate
    ln_mod<0><<<16384, 256, 0, stream>>>(out, n2g, n2b, ada, bufA);
    // 8/9. MLP: fc1 in ONE dispatch (r21 measured-best). fc2 split in two,
    //      REVERSE chunk order: chunk 1 (most recently written by fc1, L3-hot)
    //      first, then chunk 0 (cold either way).
    const size_t hid_bytes = (size_t)65536 * 2048 * 2;
    const bool single = ((char*)bufB + hid_bytes) <= ((char*)d_ws + ws_size);
    if (single) {
        gemm_bt<1><<<8192, 256, 0, stream>>>(bufA, W1, fc1_b, bufB, nullptr, 2048, 512, 0, 16);
        gemm_bt<3><<<1024, 256, 0, stream>>>(bufB + (size_t)32768 * 2048, W2, fc2_b, out, nullptr,
                                             512, 2048, 32768, 4);
        gemm_bt<3><<<1024, 256, 0, stream>>>(bufB, W2, fc2_b, out, nullptr,
                                             512, 2048, 0, 4);
    } else {
        for (int c = 0; c < 2; ++c) {
            gemm_bt<1><<<4096, 256, 0, stream>>>(bufA + (size_t)c * 32768 * 512, W1, fc1_b,
                                                 bufB, nullptr, 2048, 512, 0, 16);
            gemm_bt<3><<<1024, 256, 0, stream>>>(bufB, W2, fc2_b, out, nullptr,
                                                 512, 2048, c * 32768, 4);
        }
    }
}

// Round 24
// 729.171 us; speedup vs baseline: 1.0346x; 1.0346x over previous
//
#include <hip/hip_runtime.h>
#include <cstdint>
#include <cstddef>

typedef __bf16 bf16x8 __attribute__((ext_vector_type(8)));
typedef float f32x4 __attribute__((ext_vector_type(4)));
typedef unsigned short u16x8 __attribute__((ext_vector_type(8)));
typedef unsigned short u16x4 __attribute__((ext_vector_type(4)));

#define DEV __device__ __forceinline__

DEV unsigned short f2b(float f) {
    __bf16 b = (__bf16)f;                      // native RTNE cvt
    return __builtin_bit_cast(unsigned short, b);
}

DEV float fast_rcp(float x) { return __builtin_amdgcn_rcpf(x); }  // v_rcp_f32, ~1ulp

// sigmoid-form GELU with HW reciprocal (~6 VALU ops). Tails saturate correctly.
DEV float gelu_f(float v) {
    float e = __expf(-1.702f * v);
    return v * fast_rcp(1.f + e);
}

// ---------------------------------------------------------------- merged weight converts (one launch)
__global__ __launch_bounds__(256) void cvt_all(const float* __restrict__ s0, const float* __restrict__ s1,
                                               const float* __restrict__ s2, const float* __restrict__ s3,
                                               unsigned short* __restrict__ d0, unsigned short* __restrict__ d1,
                                               unsigned short* __restrict__ d2, unsigned short* __restrict__ d3) {
    int b = blockIdx.x;
    const float* s; unsigned short* d; int lb;
    if (b < 768)       { s = s0; d = d0; lb = b; }
    else if (b < 1024) { s = s1; d = d1; lb = b - 768; }
    else if (b < 2048) { s = s2; d = d2; lb = b - 1024; }
    else               { s = s3; d = d3; lb = b - 2048; }
    int i = lb * 256 + threadIdx.x;
    float4 f = ((const float4*)s)[i];
    u16x4 o;
    o[0] = f2b(f.x); o[1] = f2b(f.y); o[2] = f2b(f.z); o[3] = f2b(f.w);
    ((u16x4*)d)[i] = o;
}

// ---------------------------------------------------------------- rel-pos bias table: bias[h][i][j], fp32
__global__ __launch_bounds__(256) void bias_pre(const float* __restrict__ rpb, float* __restrict__ bias) {
    int idx = blockIdx.x * 256 + threadIdx.x;      // 16*4096 = 65536
    int h = idx >> 12, ij = idx & 4095;
    int i = ij >> 6, j = ij & 63;
    int r = ((i >> 3) - (j >> 3) + 7) * 15 + ((i & 7) - (j & 7) + 7);
    bias[idx] = rpb[r * 16 + h];
}

// ---------------------------------------------------------------- ada = silu(t)@W^T + b
__global__ __launch_bounds__(256) void ada_kernel(const float* __restrict__ t_emb,
                                                  const float* __restrict__ aw,
                                                  const float* __restrict__ ab,
                                                  float* __restrict__ ada) {
    __shared__ float st[512];
    int b = blockIdx.x, jc = blockIdx.y;
    for (int k = threadIdx.x; k < 512; k += 256) {
        float t = t_emb[b * 512 + k];
        st[k] = t * fast_rcp(1.f + __expf(-t));
    }
    __syncthreads();
    int j = jc * 256 + threadIdx.x;
    const float* wr = aw + (size_t)j * 512;
    float acc = ab[j];
    for (int k = 0; k < 512; ++k) acc += st[k] * wr[k];
    ada[b * 2048 + j] = acc;
}

// ---------------------------------------------------------------- LN + modulate (+roll/window for WIN=1)
template <int WIN>
__global__ __launch_bounds__(256, 4) void ln_mod(const float* __restrict__ xin,
                                                 const float* __restrict__ g,
                                                 const float* __restrict__ beta,
                                                 const float* __restrict__ ada,
                                                 unsigned short* __restrict__ out) {
    int wv = threadIdx.x >> 6, l = threadIdx.x & 63;
    int tok = blockIdx.x * 4 + wv;
    int bb;
    const float* src;
    if (WIN) {
        int w = tok >> 6, t = tok & 63;
        bb = w >> 6;
        int nw = w & 63;
        int y = (((nw >> 3) << 3) + (t >> 3) + 4) & 63;
        int x = (((nw & 7) << 3) + (t & 7) + 4) & 63;
        src = xin + ((size_t)(bb * 64 + y) * 64 + x) * 512;
    } else {
        bb = tok >> 12;
        src = xin + (size_t)tok * 512;
    }
    const float4* f4 = (const float4*)src;
    float4 v0 = f4[l * 2];
    float4 v1 = f4[l * 2 + 1];
    float s = v0.x + v0.y + v0.z + v0.w + v1.x + v1.y + v1.z + v1.w;
    float ss = v0.x * v0.x + v0.y * v0.y + v0.z * v0.z + v0.w * v0.w +
               v1.x * v1.x + v1.y * v1.y + v1.z * v1.z + v1.w * v1.w;
#pragma unroll
    for (int d = 1; d < 64; d <<= 1) {
        s += __shfl_xor(s, d, 64);
        ss += __shfl_xor(ss, d, 64);
    }
    float mean = s * (1.f / 512.f);
    float var = ss * (1.f / 512.f) - mean * mean;
    float rstd = rsqrtf(var + 1e-5f);
    const float* sh = ada + bb * 2048 + (WIN ? 0 : 1024);
    const float* sc = ada + bb * 2048 + (WIN ? 512 : 1536);
    int c = l * 8;
    u16x8 o;
#pragma unroll
    for (int q = 0; q < 8; ++q) {
        float xv = (q < 4) ? (&v0.x)[q] : (&v1.x)[q - 4];
        float nv = (xv - mean) * rstd * g[c + q] + beta[c + q];
        nv = nv * (1.f + sc[c + q]) + sh[c + q];
        o[q] = f2b(nv);
    }
    *(u16x8*)(out + (size_t)tok * 512 + c) = o;
}

// ---------------------------------------------------------------- 128x128 GEMM, BK=64, single buffer, SPLIT-KK (r14 best)
// barrier -> read kk0(8) -> 16 MFMA -> read kk1(8) -> barrier -> stage(kt+1) -> 16 MFMA.
// XOR(r&7) involution swizzle; 32KB LDS. Coalesced bf16 epilogue via LDS.
// EPI 0: +bias -> bf16                EPI 1: gelu(+bias) -> bf16
// EPI 2: +bias +window-reverse/roll +resid -> fp32   EPI 3: +bias, out += (fp32)
// EPI 4: +bias -> bf16 in head-blocked layout [w][p][h][64][32] (qkv for attn)
template <int EPI>
__global__ __launch_bounds__(256, 4) void gemm_bt(const unsigned short* __restrict__ A,
                                                  const unsigned short* __restrict__ B,
                                                  const float* __restrict__ bias,
                                                  void* __restrict__ outv,
                                                  const float* __restrict__ resid,
                                                  int N, int K, int m0g, int nbx) {
    __shared__ __align__(16) unsigned short sA[128 * 64];
    __shared__ __align__(16) unsigned short sB[128 * 64];
    const int tid = threadIdx.x;
    // T1: XCD-aware swizzle (grid always a multiple of 8)
    const int cpx = gridDim.x >> 3;
    const int wg = (blockIdx.x & 7) * cpx + (blockIdx.x >> 3);
    const int by = wg / nbx, bx = wg - by * nbx;
    const int bm = by * 128, bn = bx * 128;
    const int l = tid & 63, wv = tid >> 6;
    const int wm = (wv >> 1) * 64, wn = (wv & 1) * 64;
    const int lrow = l & 15, lg = l >> 4;

    auto stage = [&](int k0) {
#pragma unroll
        for (int inst = 0; inst < 4; ++inst) {
            int S = inst * 256 + tid;          // 16B slot in [0,1024): row r, slot j of 8
            int r = S >> 3, j = S & 7;
            int c0 = j ^ (r & 7);              // involutive swizzle on global source
            const unsigned short* gA = A + (size_t)(bm + r) * K + k0 + c0 * 8;
            __builtin_amdgcn_global_load_lds((const __attribute__((address_space(1))) void*)gA,
                                             (__attribute__((address_space(3))) void*)&sA[S * 8], 16, 0, 0);
        }
#pragma unroll
        for (int inst = 0; inst < 4; ++inst) {
            int S = inst * 256 + tid;
            int r = S >> 3, j = S & 7;
            int c0 = j ^ (r & 7);
            const unsigned short* gB = B + (size_t)(bn + r) * K + k0 + c0 * 8;
            __builtin_amdgcn_global_load_lds((const __attribute__((address_space(1))) void*)gB,
                                             (__attribute__((address_space(3))) void*)&sB[S * 8], 16, 0, 0);
        }
    };

    f32x4 acc[4][4] = {};
    const int nk = K >> 6;                     // 8 (K=512) or 32 (K=2048)
    stage(0);
    for (int kt = 0; kt < nk; ++kt) {
        __syncthreads();                       // staging of kt landed
        {
            bf16x8 a0[4], b0[4];               // kk = 0 fragments only (32 VGPR)
#pragma unroll
            for (int m = 0; m < 4; ++m) {
                int R = wm + m * 16 + lrow;
                a0[m] = *(const bf16x8*)(sA + R * 64 + ((lg ^ (R & 7)) * 8));
            }
#pragma unroll
            for (int n = 0; n < 4; ++n) {
                int C = wn + n * 16 + lrow;
                b0[n] = *(const bf16x8*)(sB + C * 64 + ((lg ^ (C & 7)) * 8));
            }
#pragma unroll
            for (int m = 0; m < 4; ++m)
#pragma unroll
                for (int n = 0; n < 4; ++n)
                    acc[m][n] = __builtin_amdgcn_mfma_f32_16x16x32_bf16(a0[m], b0[n], acc[m][n], 0, 0, 0);
        }
        bf16x8 a1[4], b1[4];                   // kk = 1 fragments
#pragma unroll
        for (int m = 0; m < 4; ++m) {
            int R = wm + m * 16 + lrow;
            a1[m] = *(const bf16x8*)(sA + R * 64 + (((4 | lg) ^ (R & 7)) * 8));
        }
#pragma unroll
        for (int n = 0; n < 4; ++n) {
            int C = wn + n * 16 + lrow;
            b1[n] = *(const bf16x8*)(sB + C * 64 + (((4 | lg) ^ (C & 7)) * 8));
        }
        __syncthreads();                       // all reads done -> buffer overwritable
        if (kt + 1 < nk) stage((kt + 1) * 64); // DMA fills while MFMA(kk1) runs
#pragma unroll
        for (int m = 0; m < 4; ++m)
#pragma unroll
            for (int n = 0; n < 4; ++n)
                acc[m][n] = __builtin_amdgcn_mfma_f32_16x16x32_bf16(a1[m], b1[n], acc[m][n], 0, 0, 0);
    }

    if constexpr (EPI == 0 || EPI == 1 || EPI == 4) {
        unsigned short* o = (unsigned short*)outv;
        unsigned short* tb = &sA[0] + wv * 1152;   // per-wave 16x72 u16
        float bv[4];
#pragma unroll
        for (int n = 0; n < 4; ++n) bv[n] = bias[bn + wn + n * 16 + lrow];
#pragma unroll
        for (int m = 0; m < 4; ++m) {
#pragma unroll
            for (int n = 0; n < 4; ++n)
#pragma unroll
                for (int r = 0; r < 4; ++r) {
                    float v = acc[m][n][r] + bv[n];
                    if constexpr (EPI == 1) v = gelu_f(v);
                    tb[(lg * 4 + r) * 72 + n * 16 + lrow] = f2b(v);
                }
#pragma unroll
            for (int it = 0; it < 2; ++it) {
                int rr = it * 8 + (l >> 3);
                int cc = (l & 7) * 8;
                u16x8 vv = *(const u16x8*)(tb + rr * 72 + cc);
                if constexpr (EPI == 4) {
                    int row = bm + wm + m * 16 + rr;
                    int col = bn + wn + cc;
                    int w_ = row >> 6, t_ = row & 63;
                    size_t dst = (size_t)w_ * 98304 + (size_t)(col >> 9) * 32768 +
                                 (size_t)((col >> 5) & 15) * 2048 + t_ * 32 + (col & 31);
                    *(u16x8*)(o + dst) = vv;
                } else {
                    *(u16x8*)(o + (size_t)(bm + wm + m * 16 + rr) * N + bn + wn + cc) = vv;
                }
            }
        }
    } else if constexpr (EPI == 2) {
        float* o = (float*)outv;
#pragma unroll
        for (int m = 0; m < 4; ++m)
#pragma unroll
            for (int r = 0; r < 4; ++r) {
                int row = bm + wm + m * 16 + lg * 4 + r;
                int wdx = row >> 6, t = row & 63;
                int bb = wdx >> 6, nw = wdx & 63;
                int Y = (((nw >> 3) << 3) + (t >> 3) + 4) & 63;
                int X = (((nw & 7) << 3) + (t & 7) + 4) & 63;
                size_t base = ((size_t)(bb * 64 + Y) * 64 + X) * 512;
#pragma unroll
                for (int n = 0; n < 4; ++n) {
                    int col = bn + wn + n * 16 + lrow;
                    o[base + col] = resid[base + col] + acc[m][n][r] + bias[col];
                }
            }
    } else {  // EPI == 3
        float* o = (float*)outv;
#pragma unroll
        for (int m = 0; m < 4; ++m)
#pragma unroll
            for (int r = 0; r < 4; ++r) {
                size_t rg = (size_t)(m0g + bm + wm + m * 16 + lg * 4 + r) * 512;
#pragma unroll
                for (int n = 0; n < 4; ++n) {
                    int col = bn + wn + n * 16 + lrow;
                    o[rg + col] += acc[m][n][r] + bias[col];
                }
            }
    }
}

// ---------------------------------------------------------------- attention: 1 wave per (window, head)
// qkv in head-blocked layout [w][p][h][64][32] -> all q/k/v reads fully coalesced.
// Output staged per-wave in LDS (stride-40 rows) -> 64B-contiguous row writes.
__global__ __launch_bounds__(256, 2) void attn_kernel(const unsigned short* __restrict__ qkv,
                                                      const float* __restrict__ bias_t,
                                                      unsigned short* __restrict__ out) {
    __shared__ __align__(16) unsigned short P_lds[4][64 * 72];
    __shared__ __align__(16) unsigned short Vt[4][32 * 72];
    const int wv = threadIdx.x >> 6, l = threadIdx.x & 63;
    const int u = blockIdx.x * 4 + wv;
    const int w = u >> 4, h = u & 15;
    const int lrow = l & 15, lg = l >> 4;
    const float SCALE = 0.17677669529663687f;  // 32^-0.5

    const unsigned short* qb = qkv + (size_t)w * 98304 + (size_t)h * 2048;

    bf16x8 qf[4], kf[4];
#pragma unroll
    for (int i = 0; i < 4; ++i) {
        qf[i] = *(const bf16x8*)(qb + (16 * i + lrow) * 32 + lg * 8);
        kf[i] = *(const bf16x8*)(qb + 32768 + (16 * i + lrow) * 32 + lg * 8);
    }
    f32x4 S[4][4] = {};
#pragma unroll
    for (int mi = 0; mi < 4; ++mi)
#pragma unroll
        for (int ni = 0; ni < 4; ++ni)
            S[mi][ni] = __builtin_amdgcn_mfma_f32_16x16x32_bf16(qf[mi], kf[ni], S[mi][ni], 0, 0, 0);

    u16x8 vreg[4];
    const unsigned short* vp = qb + 65536 + (size_t)l * 32;
#pragma unroll
    for (int d0 = 0; d0 < 4; ++d0) vreg[d0] = *(const u16x8*)(vp + d0 * 8);

    const int nw = w & 63;
    const int wh0 = (nw >> 3) << 3, ww0 = (nw & 7) << 3;
    auto region = [&](int t) -> int {
        int yy = wh0 + (t >> 3), xx = ww0 + (t & 7);
        int rh = (yy < 56) ? 0 : ((yy < 60) ? 1 : 2);
        int rw = (xx < 56) ? 0 : ((xx < 60) ? 1 : 2);
        return rh * 3 + rw;
    };
    int jreg[4], jcol[4];
#pragma unroll
    for (int ni = 0; ni < 4; ++ni) {
        jcol[ni] = 16 * ni + lrow;
        jreg[ni] = region(jcol[ni]);
    }
    const float* bh = bias_t + h * 4096;
    unsigned short* pl = &P_lds[wv][0];
#pragma unroll
    for (int mi = 0; mi < 4; ++mi)
#pragma unroll
        for (int r = 0; r < 4; ++r) {
            int i = 16 * mi + 4 * lg + r;
            int ireg = region(i);
            const float* bi = bh + i * 64;
            float pv[4];
            float mx = -1e30f;
#pragma unroll
            for (int ni = 0; ni < 4; ++ni) {
                float val = S[mi][ni][r] * SCALE + bi[jcol[ni]];
                if (ireg != jreg[ni]) val -= 100.f;
                pv[ni] = val;
                mx = fmaxf(mx, val);
            }
#pragma unroll
            for (int d = 1; d < 16; d <<= 1) mx = fmaxf(mx, __shfl_xor(mx, d, 64));
            float sum = 0.f;
#pragma unroll
            for (int ni = 0; ni < 4; ++ni) {
                pv[ni] = __expf(pv[ni] - mx);
                sum += pv[ni];
            }
#pragma unroll
            for (int d = 1; d < 16; d <<= 1) sum += __shfl_xor(sum, d, 64);
            float inv = fast_rcp(sum);         // sum >= 1, well-conditioned
#pragma unroll
            for (int ni = 0; ni < 4; ++ni) pl[i * 72 + jcol[ni]] = f2b(pv[ni] * inv);
        }

    unsigned short* vt = &Vt[wv][0];
#pragma unroll
    for (int d0 = 0; d0 < 4; ++d0)
#pragma unroll
        for (int q = 0; q < 8; ++q) vt[(d0 * 8 + q) * 72 + l] = vreg[d0][q];

    __syncthreads();

    f32x4 O[4][2] = {};
#pragma unroll
    for (int ks = 0; ks < 2; ++ks) {
        bf16x8 pa[4], vb[2];
#pragma unroll
        for (int mi = 0; mi < 4; ++mi)
            pa[mi] = *(const bf16x8*)(pl + (16 * mi + lrow) * 72 + ks * 32 + lg * 8);
#pragma unroll
        for (int ni = 0; ni < 2; ++ni)
            vb[ni] = *(const bf16x8*)(vt + (16 * ni + lrow) * 72 + ks * 32 + lg * 8);
#pragma unroll
        for (int mi = 0; mi < 4; ++mi)
#pragma unroll
            for (int ni = 0; ni < 2; ++ni)
                O[mi][ni] = __builtin_amdgcn_mfma_f32_16x16x32_bf16(pa[mi], vb[ni], O[mi][ni], 0, 0, 0);
    }

    // ---- stage O in per-wave LDS (stride 40 u16, 16B-aligned rows), then
    //      one 64B-contiguous row write per lane (replaces 32 scalar 2B stores).
    unsigned short* ostg = pl;                 // P_lds[wv] is dead now (same-wave reuse)
#pragma unroll
    for (int mi = 0; mi < 4; ++mi)
#pragma unroll
        for (int ni = 0; ni < 2; ++ni)
#pragma unroll
            for (int r = 0; r < 4; ++r)
                ostg[(16 * mi + 4 * lg + r) * 40 + 16 * ni + lrow] = f2b(O[mi][ni][r]);
    unsigned short* op = out + (size_t)(w * 64 + l) * 512 + h * 32;
#pragma unroll
    for (int q4 = 0; q4 < 4; ++q4)
        *(u16x8*)(op + q4 * 8) = *(const u16x8*)(ostg + l * 40 + q4 * 8);
}

// ---------------------------------------------------------------- launch
extern "C" void kernel_launch(void* const* d_in, const int* in_sizes, int n_in,
                              void* d_out, int out_size, void* d_ws, size_t ws_size,
                              hipStream_t stream) {
    const float* x      = (const float*)d_in[0];
    const float* t_emb  = (const float*)d_in[1];
    const float* n1g    = (const float*)d_in[2];
    const float* n1b    = (const float*)d_in[3];
    const float* qkv_w  = (const float*)d_in[4];
    const float* qkv_b  = (const float*)d_in[5];
    const float* proj_w = (const float*)d_in[6];
    const float* proj_b = (const float*)d_in[7];
    const float* rpb    = (const float*)d_in[8];
    const float* n2g    = (const float*)d_in[9];
    const float* n2b    = (const float*)d_in[10];
    const float* fc1_w  = (const float*)d_in[11];
    const float* fc1_b  = (const float*)d_in[12];
    const float* fc2_w  = (const float*)d_in[13];
    const float* fc2_b  = (const float*)d_in[14];
    const float* ada_w  = (const float*)d_in[15];
    const float* ada_b  = (const float*)d_in[16];
    float* out = (float*)d_out;

    char* p = (char*)d_ws;
    auto alloc = [&](size_t bytes) { void* r = (void*)p; p += (bytes + 255) & ~(size_t)255; return r; };
    unsigned short* Wq  = (unsigned short*)alloc((size_t)1536 * 512 * 2);
    unsigned short* Wp  = (unsigned short*)alloc((size_t)512 * 512 * 2);
    unsigned short* W1  = (unsigned short*)alloc((size_t)2048 * 512 * 2);
    unsigned short* W2  = (unsigned short*)alloc((size_t)512 * 2048 * 2);
    float*          bias_t = (float*)alloc((size_t)16 * 4096 * 4);
    float*          ada = (float*)alloc((size_t)16 * 2048 * 4);
    unsigned short* bufA = (unsigned short*)alloc((size_t)65536 * 512 * 2);   // xw / attn_out / xw2
    unsigned short* bufB = (unsigned short*)alloc((size_t)65536 * 1536 * 2);  // qkv / mlp hidden

    // 1. merged weight converts + bias table + adaLN
    cvt_all<<<3072, 256, 0, stream>>>(qkv_w, proj_w, fc1_w, fc2_w, Wq, Wp, W1, W2);
    bias_pre<<<256, 256, 0, stream>>>(rpb, bias_t);
    ada_kernel<<<dim3(16, 8), 256, 0, stream>>>(t_emb, ada_w, ada_b, ada);
    // 3. LN1 + modulate + roll + window partition
    ln_mod<1><<<16384, 256, 0, stream>>>(x, n1g, n1b, ada, bufA);
    // 4. qkv GEMM -> head-blocked layout (grid 6144, %8==0)
    gemm_bt<4><<<6144, 256, 0, stream>>>(bufA, Wq, qkv_b, bufB, nullptr, 1536, 512, 0, 12);
    // 5. windowed attention
    attn_kernel<<<4096, 256, 0, stream>>>(bufB, bias_t, bufA);
    // 6. proj GEMM + window reverse + roll + residual -> d_out (fp32)  (grid 2048)
    gemm_bt<2><<<2048, 256, 0, stream>>>(bufA, Wp, proj_b, out, x, 512, 512, 0, 4);
    // 7. LN2 + modulate
    ln_mod<0><<<16384, 256, 0, stream>>>(out, n2g, n2b, ada, bufA);
    // 8/9. MLP: single-chunk fc1 + single-chunk fc2 (r21 measured-best: 731us;
    //      r22 2-chunk=740, r23 fc2-reverse-split=754 -> chunking exploration closed).
    const size_t hid_bytes = (size_t)65536 * 2048 * 2;
    const bool single = ((char*)bufB + hid_bytes) <= ((char*)d_ws + ws_size);
    if (single) {
        gemm_bt<1><<<8192, 256, 0, stream>>>(bufA, W1, fc1_b, bufB, nullptr, 2048, 512, 0, 16);
        gemm_bt<3><<<2048, 256, 0, stream>>>(bufB, W2, fc2_b, out, nullptr, 512, 2048, 0, 4);
    } else {
        for (int c = 0; c < 2; ++c) {
            gemm_bt<1><<<4096, 256, 0, stream>>>(bufA + (size_t)c * 32768 * 512, W1, fc1_b,
                                                 bufB, nullptr, 2048, 512, 0, 16);
            gemm_bt<3><<<1024, 256, 0, stream>>>(bufB, W2, fc2_b, out, nullptr,
                                                 512, 2048, c * 32768, 4);
        }
    }
}